// Round 1
// baseline (425.763 us; speedup 1.0000x reference)
//
#include <hip/hip_runtime.h>
#include <stdint.h>

#define S_LEN 1024
#define DIM   1024
#define NHID  64
#define NHEAD 16
#define NB    4

typedef __bf16 bf16x8 __attribute__((ext_vector_type(8)));
typedef float  f32x4  __attribute__((ext_vector_type(4)));
typedef unsigned short u16;

__device__ __forceinline__ u16 f2b(float f) {
  unsigned u = __float_as_uint(f);
  u += 0x7FFFu + ((u >> 16) & 1u);          // round-to-nearest-even
  return (u16)(u >> 16);
}

__device__ __forceinline__ f32x4 mfma16(bf16x8 a, bf16x8 b, f32x4 c) {
  return __builtin_amdgcn_mfma_f32_16x16x32_bf16(a, b, c, 0, 0, 0);
}

// ---------------- prep: x -> bf16 ----------------
__global__ __launch_bounds__(256) void k_cvt_x(const float* __restrict__ x,
                                               u16* __restrict__ xb) {
  int i = blockIdx.x * 256 + threadIdx.x;     // grid sized exactly: 4096*256*4 elems
  float4 v = ((const float4*)x)[i];
  ushort4 o;
  o.x = f2b(v.x); o.y = f2b(v.y); o.z = f2b(v.z); o.w = f2b(v.w);
  ((ushort4*)xb)[i] = o;
}

// ---------------- prep: transpose f32 [batch][R][C] -> bf16 [batch][C][R] ----------------
__global__ __launch_bounds__(256) void k_transpose(const float* __restrict__ in,
                                                   u16* __restrict__ out,
                                                   int R, int C) {
  const float* ip = in + (size_t)blockIdx.x * R * C;
  u16* op = out + (size_t)blockIdx.x * R * C;
  __shared__ float tile[32][65];
  int r0 = blockIdx.y * 32, c0 = blockIdx.z * 64;
  int t = threadIdx.x;
  {
    int col = t & 63, rr = t >> 6;            // 4 rows/pass, 8 passes
#pragma unroll
    for (int p = 0; p < 8; ++p) {
      int r = p * 4 + rr;
      tile[r][col] = ip[(size_t)(r0 + r) * C + c0 + col];
    }
  }
  __syncthreads();
  {
    int d = t & 31, er = t >> 5;              // 8 out-rows/pass, 8 passes
#pragma unroll
    for (int p = 0; p < 8; ++p) {
      int e = p * 8 + er;
      op[(size_t)(c0 + e) * R + r0 + d] = f2b(tile[d][e]);
    }
  }
}

// ---------------- QKV projection: [4096,1024] @ Wt[sel][1024 n][1024 k] ----------------
// grid (32 mtiles, 8 ntiles, 3 sel), 256 threads, BM=BN=128, BK=64
__global__ __launch_bounds__(256) void k_qkv(const u16* __restrict__ xb,
                                             const u16* __restrict__ Wtb,
                                             const float* __restrict__ bq,
                                             const float* __restrict__ bk,
                                             const float* __restrict__ bv,
                                             u16* __restrict__ Qb,
                                             u16* __restrict__ Kb,
                                             u16* __restrict__ Vtb) {
  __shared__ __align__(16) char lds[32768];   // A tile 16K + W tile 16K (XOR-swizzled)
  int t = threadIdx.x, w = t >> 6, lane = t & 63;
  int l15 = lane & 15, l4 = lane >> 4;
  int m0 = blockIdx.x * 128, n0 = blockIdx.y * 128, sel = blockIdx.z;
  const u16* Wh = Wtb + (size_t)sel * (NHEAD * NHID * DIM);
  int wr = w >> 1, wc = w & 1;

  f32x4 acc[4][4];
  const f32x4 fz = {0.f, 0.f, 0.f, 0.f};
#pragma unroll
  for (int i = 0; i < 4; ++i)
#pragma unroll
    for (int j = 0; j < 4; ++j) acc[i][j] = fz;

  for (int kk = 0; kk < 16; ++kk) {
    int k0 = kk * 64;
#pragma unroll
    for (int c = 0; c < 4; ++c) {             // stage A tile: 128 rows x 128B
      int idx = c * 256 + t, r = idx >> 3, cb = idx & 7;
      int4 v = *(const int4*)(xb + (size_t)(m0 + r) * DIM + k0 + cb * 8);
      *(int4*)(lds + r * 128 + ((cb * 16) ^ ((r & 7) << 4))) = v;
    }
#pragma unroll
    for (int c = 0; c < 4; ++c) {             // stage W tile: 128 n-rows x 128B
      int idx = c * 256 + t, r = idx >> 3, cb = idx & 7;
      int4 v = *(const int4*)(Wh + (size_t)(n0 + r) * DIM + k0 + cb * 8);
      *(int4*)(lds + 16384 + r * 128 + ((cb * 16) ^ ((r & 7) << 4))) = v;
    }
    __syncthreads();
    bf16x8 a[4][2], bb[4][2];
#pragma unroll
    for (int mf = 0; mf < 4; ++mf)
#pragma unroll
      for (int kc = 0; kc < 2; ++kc) {
        int row = wr * 64 + mf * 16 + l15;
        int kb = kc * 64 + l4 * 16;
        a[mf][kc] = *(const bf16x8*)(lds + row * 128 + (kb ^ ((row & 7) << 4)));
      }
#pragma unroll
    for (int nf = 0; nf < 4; ++nf)
#pragma unroll
      for (int kc = 0; kc < 2; ++kc) {
        int row = wc * 64 + nf * 16 + l15;
        int kb = kc * 64 + l4 * 16;
        bb[nf][kc] = *(const bf16x8*)(lds + 16384 + row * 128 + (kb ^ ((row & 7) << 4)));
      }
#pragma unroll
    for (int kc = 0; kc < 2; ++kc)
#pragma unroll
      for (int mf = 0; mf < 4; ++mf)
#pragma unroll
        for (int nf = 0; nf < 4; ++nf)
          acc[mf][nf] = mfma16(a[mf][kc], bb[nf][kc], acc[mf][nf]);
    __syncthreads();
  }

  const float* bias = (sel == 0) ? bq : (sel == 1) ? bk : bv;
#pragma unroll
  for (int nf = 0; nf < 4; ++nf) {
    int n = n0 + wc * 64 + nf * 16 + l15;     // n = h*64 + e
    int h = n >> 6, e = n & 63;
    float bv_ = bias[n];
#pragma unroll
    for (int mf = 0; mf < 4; ++mf) {
      int mrow0 = m0 + wr * 64 + mf * 16 + l4 * 4;
      int b_ = mrow0 >> 10, s0 = mrow0 & 1023;
      if (sel == 2) {                          // V stored transposed [bh][e][s]
        ushort4 pk;
        pk.x = f2b(acc[mf][nf][0] + bv_);
        pk.y = f2b(acc[mf][nf][1] + bv_);
        pk.z = f2b(acc[mf][nf][2] + bv_);
        pk.w = f2b(acc[mf][nf][3] + bv_);
        *(ushort4*)(Vtb + ((size_t)(b_ * NHEAD + h) * NHID + e) * S_LEN + s0) = pk;
      } else {
        u16* dst = (sel == 0) ? Qb : Kb;       // [bh][s][e]
#pragma unroll
        for (int j = 0; j < 4; ++j)
          dst[((size_t)(b_ * NHEAD + h) * S_LEN + s0 + j) * NHID + e] =
              f2b(acc[mf][nf][j] + bv_);
      }
    }
  }
}

// ---------------- fused attention ----------------
// grid (32 qtiles, 64 bh), 256 threads = 4 waves; each wave owns a 256-key slice
__global__ __launch_bounds__(256) void k_attn(const u16* __restrict__ Qb,
                                              const u16* __restrict__ Kb,
                                              const u16* __restrict__ Vtb,
                                              const int* __restrict__ mask,
                                              float* __restrict__ alphaOut,
                                              u16* __restrict__ Ob) {
  __shared__ __align__(16) float smemf[16640]; // 64KB alpha (4x16KB) + redM/redS
  char* smem = (char*)smemf;
  float* redM = smemf + 16384;
  float* redS = smemf + 16512;
  int t = threadIdx.x, w = t >> 6, lane = t & 63;
  int l15 = lane & 15, l4 = lane >> 4;
  int q0 = blockIdx.x * 32;
  int bh = blockIdx.y, b = bh >> 4, h = bh & 15;
  const u16* Qh = Qb + (size_t)bh * S_LEN * NHID;
  const u16* Kh = Kb + (size_t)bh * S_LEN * NHID;
  const u16* Vh = Vtb + (size_t)bh * NHID * S_LEN;
  int kbase = w * 256;

  // Q fragments (A-operand): row = lane&15, k = (lane>>4)*8+j
  bf16x8 aq[2][2];
#pragma unroll
  for (int rq = 0; rq < 2; ++rq)
#pragma unroll
    for (int ec = 0; ec < 2; ++ec)
      aq[rq][ec] = *(const bf16x8*)(Qh + (size_t)(q0 + rq * 16 + l15) * NHID +
                                    ec * 32 + l4 * 8);

  // QK^T: sc[rq][kf] holds D[q=rq*16+(l>>4)*4+j][key=kf*16+(l&15)] per wave slice
  f32x4 sc[2][16];
  const f32x4 fz = {0.f, 0.f, 0.f, 0.f};
#pragma unroll
  for (int rq = 0; rq < 2; ++rq)
#pragma unroll
    for (int kf = 0; kf < 16; ++kf) sc[rq][kf] = fz;

#pragma unroll
  for (int kf = 0; kf < 16; ++kf) {
    int key = kbase + kf * 16 + l15;
    bf16x8 kb0 = *(const bf16x8*)(Kh + (size_t)key * NHID + l4 * 8);
    bf16x8 kb1 = *(const bf16x8*)(Kh + (size_t)key * NHID + 32 + l4 * 8);
#pragma unroll
    for (int rq = 0; rq < 2; ++rq) {
      sc[rq][kf] = mfma16(aq[rq][0], kb0, sc[rq][kf]);
      sc[rq][kf] = mfma16(aq[rq][1], kb1, sc[rq][kf]);
    }
  }
#pragma unroll
  for (int rq = 0; rq < 2; ++rq)
#pragma unroll
    for (int kf = 0; kf < 16; ++kf) sc[rq][kf] *= 0.5f;   // 1/SCALE

  // row max: lane-local over kf, shuffle over the 16-lane column group, LDS over waves
  float rm[2][4];
#pragma unroll
  for (int rq = 0; rq < 2; ++rq)
#pragma unroll
    for (int j = 0; j < 4; ++j) {
      float m = sc[rq][0][j];
#pragma unroll
      for (int kf = 1; kf < 16; ++kf) m = fmaxf(m, sc[rq][kf][j]);
      rm[rq][j] = m;
    }
#pragma unroll
  for (int msk = 1; msk < 16; msk <<= 1)
#pragma unroll
    for (int rq = 0; rq < 2; ++rq)
#pragma unroll
      for (int j = 0; j < 4; ++j)
        rm[rq][j] = fmaxf(rm[rq][j], __shfl_xor(rm[rq][j], msk));
  if (l15 == 0) {
#pragma unroll
    for (int rq = 0; rq < 2; ++rq)
#pragma unroll
      for (int j = 0; j < 4; ++j)
        redM[w * 32 + rq * 16 + l4 * 4 + j] = rm[rq][j];
  }
  __syncthreads();
  float Mx[2][4];
#pragma unroll
  for (int rq = 0; rq < 2; ++rq)
#pragma unroll
    for (int j = 0; j < 4; ++j) {
      int row = rq * 16 + l4 * 4 + j;
      Mx[rq][j] = fmaxf(fmaxf(redM[row], redM[32 + row]),
                        fmaxf(redM[64 + row], redM[96 + row]));
    }

  // exp + row sum
  float ls[2][4] = {{0.f, 0.f, 0.f, 0.f}, {0.f, 0.f, 0.f, 0.f}};
#pragma unroll
  for (int kf = 0; kf < 16; ++kf)
#pragma unroll
    for (int rq = 0; rq < 2; ++rq)
#pragma unroll
      for (int j = 0; j < 4; ++j) {
        float p = __expf(sc[rq][kf][j] - Mx[rq][j]);
        sc[rq][kf][j] = p;
        ls[rq][j] += p;
      }
#pragma unroll
  for (int msk = 1; msk < 16; msk <<= 1)
#pragma unroll
    for (int rq = 0; rq < 2; ++rq)
#pragma unroll
      for (int j = 0; j < 4; ++j)
        ls[rq][j] += __shfl_xor(ls[rq][j], msk);
  if (l15 == 0) {
#pragma unroll
    for (int rq = 0; rq < 2; ++rq)
#pragma unroll
      for (int j = 0; j < 4; ++j)
        redS[w * 32 + rq * 16 + l4 * 4 + j] = ls[rq][j];
  }
  __syncthreads();
  float inv[2][4];
#pragma unroll
  for (int rq = 0; rq < 2; ++rq)
#pragma unroll
    for (int j = 0; j < 4; ++j) {
      int row = rq * 16 + l4 * 4 + j;
      inv[rq][j] = 1.f / (redS[row] + redS[32 + row] + redS[64 + row] + redS[96 + row]);
    }

  // normalize, mask (post-softmax, no renorm), write alpha, stage bf16 alpha to LDS
  const int* mb = mask + (size_t)b * S_LEN * S_LEN;
  float* ab = alphaOut + (size_t)bh * S_LEN * S_LEN;
  char* myA = smem + w * 16384;
#pragma unroll
  for (int kf = 0; kf < 16; ++kf) {
    int key = kbase + kf * 16 + l15;
#pragma unroll
    for (int rq = 0; rq < 2; ++rq)
#pragma unroll
      for (int j = 0; j < 4; ++j) {
        int qloc = rq * 16 + l4 * 4 + j;
        int q = q0 + qloc;
        float av = mb[(size_t)q * S_LEN + key] ? sc[rq][kf][j] * inv[rq][j] : 0.f;
        ab[(size_t)q * S_LEN + key] = av;
        int kloc = kf * 16 + l15;
        *(u16*)(myA + qloc * 512 + ((kloc * 2) ^ ((qloc & 7) << 4))) = f2b(av);
      }
  }

  // PV over this wave's 256-key slice: o[rq][ef] partial
  f32x4 o[2][4];
#pragma unroll
  for (int rq = 0; rq < 2; ++rq)
#pragma unroll
    for (int ef = 0; ef < 4; ++ef) o[rq][ef] = fz;
#pragma unroll
  for (int kc = 0; kc < 8; ++kc) {
    bf16x8 pa[2];
#pragma unroll
    for (int rq = 0; rq < 2; ++rq) {
      int q = rq * 16 + l15;
      int kb = kc * 64 + l4 * 16;
      pa[rq] = *(const bf16x8*)(myA + q * 512 + (kb ^ ((q & 7) << 4)));
    }
#pragma unroll
    for (int ef = 0; ef < 4; ++ef) {
      int e = ef * 16 + l15;
      bf16x8 vb = *(const bf16x8*)(Vh + (size_t)e * S_LEN + kbase + kc * 32 + l4 * 8);
#pragma unroll
      for (int rq = 0; rq < 2; ++rq) o[rq][ef] = mfma16(pa[rq], vb, o[rq][ef]);
    }
  }

  // cross-wave reduction of partial O through LDS (aliases alpha region, post-barrier)
  __syncthreads();
  float* redO = smemf; // [4][32][64]
#pragma unroll
  for (int rq = 0; rq < 2; ++rq)
#pragma unroll
    for (int ef = 0; ef < 4; ++ef)
#pragma unroll
      for (int j = 0; j < 4; ++j)
        redO[w * 2048 + (rq * 16 + l4 * 4 + j) * 64 + ef * 16 + l15] = o[rq][ef][j];
  __syncthreads();
  {
    int e = t & 63, qi = t >> 6;
#pragma unroll
    for (int p = 0; p < 8; ++p) {
      int q = p * 4 + qi;
      float s4 = redO[q * 64 + e] + redO[2048 + q * 64 + e] +
                 redO[4096 + q * 64 + e] + redO[6144 + q * 64 + e];
      Ob[(size_t)(b * S_LEN + q0 + q) * DIM + h * NHID + e] = f2b(s4);
    }
  }
}

// ---------------- output projection: [4096,1024] @ Wot[1024 n][1024 k] + bo ----------------
__global__ __launch_bounds__(256) void k_oproj(const u16* __restrict__ Ob,
                                               const u16* __restrict__ Wotb,
                                               const float* __restrict__ bo,
                                               float* __restrict__ out) {
  __shared__ __align__(16) char lds[32768];
  int t = threadIdx.x, w = t >> 6, lane = t & 63;
  int l15 = lane & 15, l4 = lane >> 4;
  int m0 = blockIdx.x * 128, n0 = blockIdx.y * 128;
  int wr = w >> 1, wc = w & 1;
  f32x4 acc[4][4];
  const f32x4 fz = {0.f, 0.f, 0.f, 0.f};
#pragma unroll
  for (int i = 0; i < 4; ++i)
#pragma unroll
    for (int j = 0; j < 4; ++j) acc[i][j] = fz;

  for (int kk = 0; kk < 16; ++kk) {
    int k0 = kk * 64;
#pragma unroll
    for (int c = 0; c < 4; ++c) {
      int idx = c * 256 + t, r = idx >> 3, cb = idx & 7;
      int4 v = *(const int4*)(Ob + (size_t)(m0 + r) * DIM + k0 + cb * 8);
      *(int4*)(lds + r * 128 + ((cb * 16) ^ ((r & 7) << 4))) = v;
    }
#pragma unroll
    for (int c = 0; c < 4; ++c) {
      int idx = c * 256 + t, r = idx >> 3, cb = idx & 7;
      int4 v = *(const int4*)(Wotb + (size_t)(n0 + r) * DIM + k0 + cb * 8);
      *(int4*)(lds + 16384 + r * 128 + ((cb * 16) ^ ((r & 7) << 4))) = v;
    }
    __syncthreads();
    bf16x8 a[4][2], bb[4][2];
#pragma unroll
    for (int mf = 0; mf < 4; ++mf)
#pragma unroll
      for (int kc = 0; kc < 2; ++kc) {
        int row = wr * 64 + mf * 16 + l15;
        int kb = kc * 64 + l4 * 16;
        a[mf][kc] = *(const bf16x8*)(lds + row * 128 + (kb ^ ((row & 7) << 4)));
      }
#pragma unroll
    for (int nf = 0; nf < 4; ++nf)
#pragma unroll
      for (int kc = 0; kc < 2; ++kc) {
        int row = wc * 64 + nf * 16 + l15;
        int kb = kc * 64 + l4 * 16;
        bb[nf][kc] = *(const bf16x8*)(lds + 16384 + row * 128 + (kb ^ ((row & 7) << 4)));
      }
#pragma unroll
    for (int kc = 0; kc < 2; ++kc)
#pragma unroll
      for (int mf = 0; mf < 4; ++mf)
#pragma unroll
        for (int nf = 0; nf < 4; ++nf)
          acc[mf][nf] = mfma16(a[mf][kc], bb[nf][kc], acc[mf][nf]);
    __syncthreads();
  }
#pragma unroll
  for (int nf = 0; nf < 4; ++nf) {
    int n = n0 + wc * 64 + nf * 16 + l15;
    float bv_ = bo[n];
#pragma unroll
    for (int mf = 0; mf < 4; ++mf)
#pragma unroll
      for (int j = 0; j < 4; ++j) {
        int m = m0 + wr * 64 + mf * 16 + l4 * 4 + j;
        out[(size_t)m * DIM + n] = acc[mf][nf][j] + bv_;
      }
  }
}

extern "C" void kernel_launch(void* const* d_in, const int* in_sizes, int n_in,
                              void* d_out, int out_size, void* d_ws, size_t ws_size,
                              hipStream_t stream) {
  const float* x    = (const float*)d_in[0];
  const int*   mask = (const int*)d_in[1];
  const float* Wq   = (const float*)d_in[2];
  const float* bq   = (const float*)d_in[3];
  const float* Wk   = (const float*)d_in[4];
  const float* bk   = (const float*)d_in[5];
  const float* Wv   = (const float*)d_in[6];
  const float* bv   = (const float*)d_in[7];
  const float* Wo   = (const float*)d_in[8];
  const float* bo   = (const float*)d_in[9];
  float* out = (float*)d_out;
  float* alphaOut = out + (size_t)NB * S_LEN * DIM; // output 0 then alpha

  char* ws = (char*)d_ws;
  u16* xb   = (u16*)(ws);             // 8,388,608 B  [4096][1024] bf16
  u16* Wtb  = (u16*)(ws + 8388608);   // 6,291,456 B  [3][16][64 e][1024 d]
  u16* Wotb = (u16*)(ws + 14680064);  // 2,097,152 B  [1024 n][1024 k]
  u16* Qb   = (u16*)(ws + 16777216);  // 8,388,608 B  [64 bh][1024 s][64 e]
  u16* Kb   = (u16*)(ws + 25165824);  // 8,388,608 B
  u16* Vtb  = (u16*)(ws + 33554432);  // 8,388,608 B  [64 bh][64 e][1024 s]
  u16* Ob   = (u16*)(ws + 41943040);  // 8,388,608 B  [4096][1024]

  k_cvt_x<<<4096, 256, 0, stream>>>(x, xb);
  k_transpose<<<dim3(16, 32, 1), 256, 0, stream>>>(Wq, Wtb,           1024, 64);
  k_transpose<<<dim3(16, 32, 1), 256, 0, stream>>>(Wk, Wtb + 1048576, 1024, 64);
  k_transpose<<<dim3(16, 32, 1), 256, 0, stream>>>(Wv, Wtb + 2097152, 1024, 64);
  k_transpose<<<dim3(1, 32, 16), 256, 0, stream>>>(Wo, Wotb,          1024, 1024);
  k_qkv<<<dim3(32, 8, 3), 256, 0, stream>>>(xb, Wtb, bq, bk, bv, Qb, Kb, Vtb);
  k_attn<<<dim3(32, 64), 256, 0, stream>>>(Qb, Kb, Vtb, mask, alphaOut, Ob);
  k_oproj<<<dim3(32, 8), 256, 0, stream>>>(Ob, Wotb, bo, out);
}

// Round 2
// 265.042 us; speedup vs baseline: 1.6064x; 1.6064x over previous
//
#include <hip/hip_runtime.h>
#include <stdint.h>

#define S_LEN 1024
#define DIM   1024
#define NHID  64
#define NHEAD 16
#define NB    4

typedef __bf16 bf16x8 __attribute__((ext_vector_type(8)));
typedef float  f32x4  __attribute__((ext_vector_type(4)));
typedef unsigned short u16;

__device__ __forceinline__ u16 f2b(float f) {
  unsigned u = __float_as_uint(f);
  u += 0x7FFFu + ((u >> 16) & 1u);          // round-to-nearest-even
  return (u16)(u >> 16);
}

__device__ __forceinline__ f32x4 mfma16(bf16x8 a, bf16x8 b, f32x4 c) {
  return __builtin_amdgcn_mfma_f32_16x16x32_bf16(a, b, c, 0, 0, 0);
}

// ---------------- prep: x -> bf16 ----------------
__global__ __launch_bounds__(256) void k_cvt_x(const float* __restrict__ x,
                                               u16* __restrict__ xb) {
  int i = blockIdx.x * 256 + threadIdx.x;
  float4 v = ((const float4*)x)[i];
  ushort4 o;
  o.x = f2b(v.x); o.y = f2b(v.y); o.z = f2b(v.z); o.w = f2b(v.w);
  ((ushort4*)xb)[i] = o;
}

// ---------------- prep: pack mask int32 -> bitmask u32 ----------------
// one thread per output word (32 mask ints). total words = 4*1024*32 = 131072
__global__ __launch_bounds__(256) void k_maskbits(const int* __restrict__ mask,
                                                  uint32_t* __restrict__ bits) {
  int w = blockIdx.x * 256 + threadIdx.x;
  const int4* mp = (const int4*)mask + (size_t)w * 8;
  uint32_t v = 0;
#pragma unroll
  for (int i = 0; i < 8; ++i) {
    int4 m = mp[i];
    v |= (m.x != 0 ? 1u : 0u) << (i * 4 + 0);
    v |= (m.y != 0 ? 1u : 0u) << (i * 4 + 1);
    v |= (m.z != 0 ? 1u : 0u) << (i * 4 + 2);
    v |= (m.w != 0 ? 1u : 0u) << (i * 4 + 3);
  }
  bits[w] = v;
}

// ---------------- prep: transpose f32 [batch][R][C] -> bf16 [batch][C][R] ----------------
__global__ __launch_bounds__(256) void k_transpose(const float* __restrict__ in,
                                                   u16* __restrict__ out,
                                                   int R, int C) {
  const float* ip = in + (size_t)blockIdx.x * R * C;
  u16* op = out + (size_t)blockIdx.x * R * C;
  __shared__ float tile[32][65];
  int r0 = blockIdx.y * 32, c0 = blockIdx.z * 64;
  int t = threadIdx.x;
  {
    int col = t & 63, rr = t >> 6;
#pragma unroll
    for (int p = 0; p < 8; ++p) {
      int r = p * 4 + rr;
      tile[r][col] = ip[(size_t)(r0 + r) * C + c0 + col];
    }
  }
  __syncthreads();
  {
    int d = t & 31, er = t >> 5;
#pragma unroll
    for (int p = 0; p < 8; ++p) {
      int e = p * 8 + er;
      op[(size_t)(c0 + e) * R + r0 + d] = f2b(tile[d][e]);
    }
  }
}

// ---------------- QKV projection: [4096,1024] @ Wt[sel][1024 n][1024 k] ----------------
// Q output is pre-scaled by 0.5 (folds softmax 1/SCALE; exact in bf16)
__global__ __launch_bounds__(256) void k_qkv(const u16* __restrict__ xb,
                                             const u16* __restrict__ Wtb,
                                             const float* __restrict__ bq,
                                             const float* __restrict__ bk,
                                             const float* __restrict__ bv,
                                             u16* __restrict__ Qb,
                                             u16* __restrict__ Kb,
                                             u16* __restrict__ Vtb) {
  __shared__ __align__(16) char lds[32768];
  int t = threadIdx.x, w = t >> 6, lane = t & 63;
  int l15 = lane & 15, l4 = lane >> 4;
  int m0 = blockIdx.x * 128, n0 = blockIdx.y * 128, sel = blockIdx.z;
  const u16* Wh = Wtb + (size_t)sel * (NHEAD * NHID * DIM);
  int wr = w >> 1, wc = w & 1;

  f32x4 acc[4][4];
  const f32x4 fz = {0.f, 0.f, 0.f, 0.f};
#pragma unroll
  for (int i = 0; i < 4; ++i)
#pragma unroll
    for (int j = 0; j < 4; ++j) acc[i][j] = fz;

  for (int kk = 0; kk < 16; ++kk) {
    int k0 = kk * 64;
#pragma unroll
    for (int c = 0; c < 4; ++c) {
      int idx = c * 256 + t, r = idx >> 3, cb = idx & 7;
      int4 v = *(const int4*)(xb + (size_t)(m0 + r) * DIM + k0 + cb * 8);
      *(int4*)(lds + r * 128 + ((cb * 16) ^ ((r & 7) << 4))) = v;
    }
#pragma unroll
    for (int c = 0; c < 4; ++c) {
      int idx = c * 256 + t, r = idx >> 3, cb = idx & 7;
      int4 v = *(const int4*)(Wh + (size_t)(n0 + r) * DIM + k0 + cb * 8);
      *(int4*)(lds + 16384 + r * 128 + ((cb * 16) ^ ((r & 7) << 4))) = v;
    }
    __syncthreads();
    bf16x8 a[4][2], bb[4][2];
#pragma unroll
    for (int mf = 0; mf < 4; ++mf)
#pragma unroll
      for (int kc = 0; kc < 2; ++kc) {
        int row = wr * 64 + mf * 16 + l15;
        int kb = kc * 64 + l4 * 16;
        a[mf][kc] = *(const bf16x8*)(lds + row * 128 + (kb ^ ((row & 7) << 4)));
      }
#pragma unroll
    for (int nf = 0; nf < 4; ++nf)
#pragma unroll
      for (int kc = 0; kc < 2; ++kc) {
        int row = wc * 64 + nf * 16 + l15;
        int kb = kc * 64 + l4 * 16;
        bb[nf][kc] = *(const bf16x8*)(lds + 16384 + row * 128 + (kb ^ ((row & 7) << 4)));
      }
#pragma unroll
    for (int kc = 0; kc < 2; ++kc)
#pragma unroll
      for (int mf = 0; mf < 4; ++mf)
#pragma unroll
        for (int nf = 0; nf < 4; ++nf)
          acc[mf][nf] = mfma16(a[mf][kc], bb[nf][kc], acc[mf][nf]);
    __syncthreads();
  }

  const float* bias = (sel == 0) ? bq : (sel == 1) ? bk : bv;
  float postScale = (sel == 0) ? 0.5f : 1.0f;
#pragma unroll
  for (int nf = 0; nf < 4; ++nf) {
    int n = n0 + wc * 64 + nf * 16 + l15;
    int h = n >> 6, e = n & 63;
    float bv_ = bias[n];
#pragma unroll
    for (int mf = 0; mf < 4; ++mf) {
      int mrow0 = m0 + wr * 64 + mf * 16 + l4 * 4;
      int b_ = mrow0 >> 10, s0 = mrow0 & 1023;
      if (sel == 2) {
        ushort4 pk;
        pk.x = f2b(acc[mf][nf][0] + bv_);
        pk.y = f2b(acc[mf][nf][1] + bv_);
        pk.z = f2b(acc[mf][nf][2] + bv_);
        pk.w = f2b(acc[mf][nf][3] + bv_);
        *(ushort4*)(Vtb + ((size_t)(b_ * NHEAD + h) * NHID + e) * S_LEN + s0) = pk;
      } else {
        u16* dst = (sel == 0) ? Qb : Kb;
#pragma unroll
        for (int j = 0; j < 4; ++j)
          dst[((size_t)(b_ * NHEAD + h) * S_LEN + s0 + j) * NHID + e] =
              f2b((acc[mf][nf][j] + bv_) * postScale);
      }
    }
  }
}

// ---------------- fused attention ----------------
// grid (32 qtiles, 64 bh), 4 waves; wave owns 256-key slice.
// LDS: maskbits 32x33 u32 (4224B pad+1) | redM 512B | redS 512B | chunks 4w x 2buf x 4KB
__global__ __launch_bounds__(256) void k_attn(const u16* __restrict__ Qb,
                                              const u16* __restrict__ Kb,
                                              const u16* __restrict__ Vtb,
                                              const uint32_t* __restrict__ mbitsG,
                                              float* __restrict__ alphaOut,
                                              u16* __restrict__ Ob) {
  __shared__ __align__(16) char smem[38016];
  uint32_t* mbits = (uint32_t*)smem;        // [32 q][33 words] (padded)
  float* redM = (float*)(smem + 4224);      // [128]
  float* redS = (float*)(smem + 4736);      // [128]
  char* chunkB = smem + 5248;               // [4 w][2 buf][4096]
  int t = threadIdx.x, w = t >> 6, lane = t & 63;
  int l15 = lane & 15, l4 = lane >> 4;
  int q0 = blockIdx.x * 32;
  int bh = blockIdx.y, b = bh >> 4, hh = bh & 15;
  const u16* Qh = Qb + (size_t)bh * S_LEN * NHID;
  const u16* Kh = Kb + (size_t)bh * S_LEN * NHID;
  const u16* Vh = Vtb + (size_t)bh * NHID * S_LEN;
  int kbase = w * 256;

  // issue mask-bit load early (4KB coalesced per block)
  uint4 mw4 = ((const uint4*)(mbitsG + ((size_t)b * S_LEN + q0) * 32))[t];

  // Q fragments (pre-scaled by 0.5)
  bf16x8 aq[2][2];
#pragma unroll
  for (int rq = 0; rq < 2; ++rq)
#pragma unroll
    for (int ec = 0; ec < 2; ++ec)
      aq[rq][ec] = *(const bf16x8*)(Qh + (size_t)(q0 + rq * 16 + l15) * NHID +
                                    ec * 32 + l4 * 8);

  // stash mask bits to LDS (padded rows); barrier comes with redM sync
  {
    int row = t >> 3, c0 = (t & 7) * 4;
    mbits[row * 33 + c0 + 0] = mw4.x;
    mbits[row * 33 + c0 + 1] = mw4.y;
    mbits[row * 33 + c0 + 2] = mw4.z;
    mbits[row * 33 + c0 + 3] = mw4.w;
  }

  // QK^T
  f32x4 sc[2][16];
  const f32x4 fz = {0.f, 0.f, 0.f, 0.f};
#pragma unroll
  for (int rq = 0; rq < 2; ++rq)
#pragma unroll
    for (int kf = 0; kf < 16; ++kf) sc[rq][kf] = fz;

#pragma unroll
  for (int kf = 0; kf < 16; ++kf) {
    int key = kbase + kf * 16 + l15;
    bf16x8 kb0 = *(const bf16x8*)(Kh + (size_t)key * NHID + l4 * 8);
    bf16x8 kb1 = *(const bf16x8*)(Kh + (size_t)key * NHID + 32 + l4 * 8);
#pragma unroll
    for (int rq = 0; rq < 2; ++rq) {
      sc[rq][kf] = mfma16(aq[rq][0], kb0, sc[rq][kf]);
      sc[rq][kf] = mfma16(aq[rq][1], kb1, sc[rq][kf]);
    }
  }

  // row max (lane-local -> 16-lane shuffle -> cross-wave via LDS)
  float rm[2][4];
#pragma unroll
  for (int rq = 0; rq < 2; ++rq)
#pragma unroll
    for (int j = 0; j < 4; ++j) {
      float m = sc[rq][0][j];
#pragma unroll
      for (int kf = 1; kf < 16; ++kf) m = fmaxf(m, sc[rq][kf][j]);
      rm[rq][j] = m;
    }
#pragma unroll
  for (int msk = 1; msk < 16; msk <<= 1)
#pragma unroll
    for (int rq = 0; rq < 2; ++rq)
#pragma unroll
      for (int j = 0; j < 4; ++j)
        rm[rq][j] = fmaxf(rm[rq][j], __shfl_xor(rm[rq][j], msk));
  if (l15 == 0) {
#pragma unroll
    for (int rq = 0; rq < 2; ++rq)
#pragma unroll
      for (int j = 0; j < 4; ++j)
        redM[w * 32 + rq * 16 + l4 * 4 + j] = rm[rq][j];
  }
  __syncthreads();
  float Mx[2][4];
#pragma unroll
  for (int rq = 0; rq < 2; ++rq)
#pragma unroll
    for (int j = 0; j < 4; ++j) {
      int row = rq * 16 + l4 * 4 + j;
      Mx[rq][j] = fmaxf(fmaxf(redM[row], redM[32 + row]),
                        fmaxf(redM[64 + row], redM[96 + row]));
    }

  // exp + row sum
  float ls[2][4] = {{0.f, 0.f, 0.f, 0.f}, {0.f, 0.f, 0.f, 0.f}};
#pragma unroll
  for (int kf = 0; kf < 16; ++kf)
#pragma unroll
    for (int rq = 0; rq < 2; ++rq)
#pragma unroll
      for (int j = 0; j < 4; ++j) {
        float p = __expf(sc[rq][kf][j] - Mx[rq][j]);
        sc[rq][kf][j] = p;
        ls[rq][j] += p;
      }
#pragma unroll
  for (int msk = 1; msk < 16; msk <<= 1)
#pragma unroll
    for (int rq = 0; rq < 2; ++rq)
#pragma unroll
      for (int j = 0; j < 4; ++j)
        ls[rq][j] += __shfl_xor(ls[rq][j], msk);
  if (l15 == 0) {
#pragma unroll
    for (int rq = 0; rq < 2; ++rq)
#pragma unroll
      for (int j = 0; j < 4; ++j)
        redS[w * 32 + rq * 16 + l4 * 4 + j] = ls[rq][j];
  }
  __syncthreads();
  float inv[2][4];
#pragma unroll
  for (int rq = 0; rq < 2; ++rq)
#pragma unroll
    for (int j = 0; j < 4; ++j) {
      int row = rq * 16 + l4 * 4 + j;
      inv[rq][j] = 1.f / (redS[row] + redS[32 + row] + redS[64 + row] + redS[96 + row]);
    }

  const float* ab = nullptr; // silence unused warnings pattern
  float* abW = alphaOut + (size_t)bh * S_LEN * S_LEN;
  (void)ab;

  f32x4 o[2][4];
#pragma unroll
  for (int rq = 0; rq < 2; ++rq)
#pragma unroll
    for (int ef = 0; ef < 4; ++ef) o[rq][ef] = fz;

  // chunk = 64 keys. produce: mask+normalize+global write+LDS bf16 stage.
  auto produce = [&](int c) {
    char* buf = chunkB + (w * 2 + (c & 1)) * 4096;
    int widxBase = (kbase >> 5) + c * 2;
#pragma unroll
    for (int f = 0; f < 4; ++f) {
      int kf = c * 4 + f;
      int keyg = kbase + kf * 16 + l15;
      int widx = widxBase + (f >> 1);
      int bitpos = ((f & 1) << 4) + l15;
#pragma unroll
      for (int rq = 0; rq < 2; ++rq)
#pragma unroll
        for (int j = 0; j < 4; ++j) {
          int qloc = rq * 16 + l4 * 4 + j;
          uint32_t mwd = mbits[qloc * 33 + widx];
          float av = ((mwd >> bitpos) & 1u) ? sc[rq][kf][j] * inv[rq][j] : 0.f;
          __builtin_nontemporal_store(av, abW + (size_t)(q0 + qloc) * S_LEN + keyg);
          int klc = f * 16 + l15;
          *(u16*)(buf + qloc * 128 + ((2 * klc) ^ ((qloc & 7) << 4))) = f2b(av);
        }
    }
  };
  auto pv = [&](int c) {
    char* buf = chunkB + (w * 2 + (c & 1)) * 4096;
#pragma unroll
    for (int kc2 = 0; kc2 < 2; ++kc2) {
      bf16x8 pa[2];
#pragma unroll
      for (int rq = 0; rq < 2; ++rq) {
        int qloc = rq * 16 + l15;
        pa[rq] = *(const bf16x8*)(buf + qloc * 128 +
                                  ((kc2 * 64 + l4 * 16) ^ ((qloc & 7) << 4)));
      }
#pragma unroll
      for (int ef = 0; ef < 4; ++ef) {
        int e = ef * 16 + l15;
        bf16x8 vb = *(const bf16x8*)(Vh + (size_t)e * S_LEN + kbase + c * 64 +
                                     kc2 * 32 + l4 * 8);
#pragma unroll
        for (int rq = 0; rq < 2; ++rq) o[rq][ef] = mfma16(pa[rq], vb, o[rq][ef]);
      }
    }
  };

  produce(0);
  produce(1); pv(0);
  produce(2); pv(1);
  produce(3); pv(2);
  pv(3);

  // cross-wave O reduction in 2 halves (16KB, aliases chunk region)
  __syncthreads();
  float* redO = (float*)(smem + 5248); // [4 w][16 q][64 e]
#pragma unroll
  for (int rq = 0; rq < 2; ++rq) {
#pragma unroll
    for (int ef = 0; ef < 4; ++ef)
#pragma unroll
      for (int j = 0; j < 4; ++j)
        redO[(w * 16 + l4 * 4 + j) * 64 + ef * 16 + l15] = o[rq][ef][j];
    __syncthreads();
    {
      int e = t & 63, r4 = t >> 6;
#pragma unroll
      for (int p = 0; p < 4; ++p) {
        int r = p * 4 + r4;
        float s4 = redO[r * 64 + e] + redO[(16 + r) * 64 + e] +
                   redO[(32 + r) * 64 + e] + redO[(48 + r) * 64 + e];
        Ob[(size_t)(b * S_LEN + q0 + rq * 16 + r) * DIM + hh * NHID + e] = f2b(s4);
      }
    }
    __syncthreads();
  }
}

// ---------------- output projection ----------------
__global__ __launch_bounds__(256) void k_oproj(const u16* __restrict__ Ob,
                                               const u16* __restrict__ Wotb,
                                               const float* __restrict__ bo,
                                               float* __restrict__ out) {
  __shared__ __align__(16) char lds[32768];
  int t = threadIdx.x, w = t >> 6, lane = t & 63;
  int l15 = lane & 15, l4 = lane >> 4;
  int m0 = blockIdx.x * 128, n0 = blockIdx.y * 128;
  int wr = w >> 1, wc = w & 1;
  f32x4 acc[4][4];
  const f32x4 fz = {0.f, 0.f, 0.f, 0.f};
#pragma unroll
  for (int i = 0; i < 4; ++i)
#pragma unroll
    for (int j = 0; j < 4; ++j) acc[i][j] = fz;

  for (int kk = 0; kk < 16; ++kk) {
    int k0 = kk * 64;
#pragma unroll
    for (int c = 0; c < 4; ++c) {
      int idx = c * 256 + t, r = idx >> 3, cb = idx & 7;
      int4 v = *(const int4*)(Ob + (size_t)(m0 + r) * DIM + k0 + cb * 8);
      *(int4*)(lds + r * 128 + ((cb * 16) ^ ((r & 7) << 4))) = v;
    }
#pragma unroll
    for (int c = 0; c < 4; ++c) {
      int idx = c * 256 + t, r = idx >> 3, cb = idx & 7;
      int4 v = *(const int4*)(Wotb + (size_t)(n0 + r) * DIM + k0 + cb * 8);
      *(int4*)(lds + 16384 + r * 128 + ((cb * 16) ^ ((r & 7) << 4))) = v;
    }
    __syncthreads();
    bf16x8 a[4][2], bb[4][2];
#pragma unroll
    for (int mf = 0; mf < 4; ++mf)
#pragma unroll
      for (int kc = 0; kc < 2; ++kc) {
        int row = wr * 64 + mf * 16 + l15;
        int kb = kc * 64 + l4 * 16;
        a[mf][kc] = *(const bf16x8*)(lds + row * 128 + (kb ^ ((row & 7) << 4)));
      }
#pragma unroll
    for (int nf = 0; nf < 4; ++nf)
#pragma unroll
      for (int kc = 0; kc < 2; ++kc) {
        int row = wc * 64 + nf * 16 + l15;
        int kb = kc * 64 + l4 * 16;
        bb[nf][kc] = *(const bf16x8*)(lds + 16384 + row * 128 + (kb ^ ((row & 7) << 4)));
      }
#pragma unroll
    for (int kc = 0; kc < 2; ++kc)
#pragma unroll
      for (int mf = 0; mf < 4; ++mf)
#pragma unroll
        for (int nf = 0; nf < 4; ++nf)
          acc[mf][nf] = mfma16(a[mf][kc], bb[nf][kc], acc[mf][nf]);
    __syncthreads();
  }
#pragma unroll
  for (int nf = 0; nf < 4; ++nf) {
    int n = n0 + wc * 64 + nf * 16 + l15;
    float bv_ = bo[n];
#pragma unroll
    for (int mf = 0; mf < 4; ++mf)
#pragma unroll
      for (int j = 0; j < 4; ++j) {
        int m = m0 + wr * 64 + mf * 16 + l4 * 4 + j;
        out[(size_t)m * DIM + n] = acc[mf][nf][j] + bv_;
      }
  }
}

extern "C" void kernel_launch(void* const* d_in, const int* in_sizes, int n_in,
                              void* d_out, int out_size, void* d_ws, size_t ws_size,
                              hipStream_t stream) {
  const float* x    = (const float*)d_in[0];
  const int*   mask = (const int*)d_in[1];
  const float* Wq   = (const float*)d_in[2];
  const float* bq   = (const float*)d_in[3];
  const float* Wk   = (const float*)d_in[4];
  const float* bk   = (const float*)d_in[5];
  const float* Wv   = (const float*)d_in[6];
  const float* bv   = (const float*)d_in[7];
  const float* Wo   = (const float*)d_in[8];
  const float* bo   = (const float*)d_in[9];
  float* out = (float*)d_out;
  float* alphaOut = out + (size_t)NB * S_LEN * DIM;

  char* ws = (char*)d_ws;
  u16* xb    = (u16*)(ws);             // 8,388,608 B
  u16* Wtb   = (u16*)(ws + 8388608);   // 6,291,456 B
  u16* Wotb  = (u16*)(ws + 14680064);  // 2,097,152 B
  u16* Qb    = (u16*)(ws + 16777216);  // 8,388,608 B
  u16* Kb    = (u16*)(ws + 25165824);  // 8,388,608 B
  u16* Vtb   = (u16*)(ws + 33554432);  // 8,388,608 B
  u16* Ob    = (u16*)(ws + 41943040);  // 8,388,608 B
  uint32_t* mbits = (uint32_t*)(ws + 50331648); // 524,288 B

  k_maskbits<<<512, 256, 0, stream>>>(mask, mbits);
  k_cvt_x<<<4096, 256, 0, stream>>>(x, xb);
  k_transpose<<<dim3(16, 32, 1), 256, 0, stream>>>(Wq, Wtb,           1024, 64);
  k_transpose<<<dim3(16, 32, 1), 256, 0, stream>>>(Wk, Wtb + 1048576, 1024, 64);
  k_transpose<<<dim3(16, 32, 1), 256, 0, stream>>>(Wv, Wtb + 2097152, 1024, 64);
  k_transpose<<<dim3(1, 32, 16), 256, 0, stream>>>(Wo, Wotb,          1024, 1024);
  k_qkv<<<dim3(32, 8, 3), 256, 0, stream>>>(xb, Wtb, bq, bk, bv, Qb, Kb, Vtb);
  k_attn<<<dim3(32, 64), 256, 0, stream>>>(Qb, Kb, Vtb, mbits, alphaOut, Ob);
  k_oproj<<<dim3(32, 8), 256, 0, stream>>>(Ob, Wotb, bo, out);
}

// Round 3
// 226.070 us; speedup vs baseline: 1.8833x; 1.1724x over previous
//
#include <hip/hip_runtime.h>
#include <stdint.h>

#define S_LEN 1024
#define DIM   1024
#define NHID  64
#define NHEAD 16
#define NB    4

typedef __bf16 bf16x8 __attribute__((ext_vector_type(8)));
typedef float  f32x4  __attribute__((ext_vector_type(4)));
typedef unsigned short u16;

__device__ __forceinline__ u16 f2b(float f) {
  unsigned u = __float_as_uint(f);
  u += 0x7FFFu + ((u >> 16) & 1u);          // round-to-nearest-even
  return (u16)(u >> 16);
}

__device__ __forceinline__ f32x4 mfma16(bf16x8 a, bf16x8 b, f32x4 c) {
  return __builtin_amdgcn_mfma_f32_16x16x32_bf16(a, b, c, 0, 0, 0);
}

// ---------------- prep: x -> bf16 ----------------
__global__ __launch_bounds__(256) void k_cvt_x(const float* __restrict__ x,
                                               u16* __restrict__ xb) {
  int i = blockIdx.x * 256 + threadIdx.x;
  float4 v = ((const float4*)x)[i];
  ushort4 o;
  o.x = f2b(v.x); o.y = f2b(v.y); o.z = f2b(v.z); o.w = f2b(v.w);
  ((ushort4*)xb)[i] = o;
}

// ---------------- prep: pack mask int32 -> bitmask u32 ----------------
__global__ __launch_bounds__(256) void k_maskbits(const int* __restrict__ mask,
                                                  uint32_t* __restrict__ bits) {
  int w = blockIdx.x * 256 + threadIdx.x;
  const int4* mp = (const int4*)mask + (size_t)w * 8;
  uint32_t v = 0;
#pragma unroll
  for (int i = 0; i < 8; ++i) {
    int4 m = mp[i];
    v |= (m.x != 0 ? 1u : 0u) << (i * 4 + 0);
    v |= (m.y != 0 ? 1u : 0u) << (i * 4 + 1);
    v |= (m.z != 0 ? 1u : 0u) << (i * 4 + 2);
    v |= (m.w != 0 ? 1u : 0u) << (i * 4 + 3);
  }
  bits[w] = v;
}

// ---------------- prep: transpose f32 [batch][R][C] -> bf16 [batch][C][R] ----------------
__global__ __launch_bounds__(256) void k_transpose(const float* __restrict__ in,
                                                   u16* __restrict__ out,
                                                   int R, int C) {
  const float* ip = in + (size_t)blockIdx.x * R * C;
  u16* op = out + (size_t)blockIdx.x * R * C;
  __shared__ float tile[32][65];
  int r0 = blockIdx.y * 32, c0 = blockIdx.z * 64;
  int t = threadIdx.x;
  {
    int col = t & 63, rr = t >> 6;
#pragma unroll
    for (int p = 0; p < 8; ++p) {
      int r = p * 4 + rr;
      tile[r][col] = ip[(size_t)(r0 + r) * C + c0 + col];
    }
  }
  __syncthreads();
  {
    int d = t & 31, er = t >> 5;
#pragma unroll
    for (int p = 0; p < 8; ++p) {
      int e = p * 8 + er;
      op[(size_t)(c0 + e) * R + r0 + d] = f2b(tile[d][e]);
    }
  }
}

// ---------------- QKV projection: [4096,1024] @ Wt[sel][1024 n][1024 k] ----------------
// Q output is pre-scaled by 0.5 (folds softmax 1/SCALE; exact in bf16)
__global__ __launch_bounds__(256) void k_qkv(const u16* __restrict__ xb,
                                             const u16* __restrict__ Wtb,
                                             const float* __restrict__ bq,
                                             const float* __restrict__ bk,
                                             const float* __restrict__ bv,
                                             u16* __restrict__ Qb,
                                             u16* __restrict__ Kb,
                                             u16* __restrict__ Vtb) {
  __shared__ __align__(16) char lds[32768];
  int t = threadIdx.x, w = t >> 6, lane = t & 63;
  int l15 = lane & 15, l4 = lane >> 4;
  int m0 = blockIdx.x * 128, n0 = blockIdx.y * 128, sel = blockIdx.z;
  const u16* Wh = Wtb + (size_t)sel * (NHEAD * NHID * DIM);
  int wr = w >> 1, wc = w & 1;

  f32x4 acc[4][4];
  const f32x4 fz = {0.f, 0.f, 0.f, 0.f};
#pragma unroll
  for (int i = 0; i < 4; ++i)
#pragma unroll
    for (int j = 0; j < 4; ++j) acc[i][j] = fz;

  for (int kk = 0; kk < 16; ++kk) {
    int k0 = kk * 64;
#pragma unroll
    for (int c = 0; c < 4; ++c) {
      int idx = c * 256 + t, r = idx >> 3, cb = idx & 7;
      int4 v = *(const int4*)(xb + (size_t)(m0 + r) * DIM + k0 + cb * 8);
      *(int4*)(lds + r * 128 + ((cb * 16) ^ ((r & 7) << 4))) = v;
    }
#pragma unroll
    for (int c = 0; c < 4; ++c) {
      int idx = c * 256 + t, r = idx >> 3, cb = idx & 7;
      int4 v = *(const int4*)(Wh + (size_t)(n0 + r) * DIM + k0 + cb * 8);
      *(int4*)(lds + 16384 + r * 128 + ((cb * 16) ^ ((r & 7) << 4))) = v;
    }
    __syncthreads();
    bf16x8 a[4][2], bb[4][2];
#pragma unroll
    for (int mf = 0; mf < 4; ++mf)
#pragma unroll
      for (int kc = 0; kc < 2; ++kc) {
        int row = wr * 64 + mf * 16 + l15;
        int kb = kc * 64 + l4 * 16;
        a[mf][kc] = *(const bf16x8*)(lds + row * 128 + (kb ^ ((row & 7) << 4)));
      }
#pragma unroll
    for (int nf = 0; nf < 4; ++nf)
#pragma unroll
      for (int kc = 0; kc < 2; ++kc) {
        int row = wc * 64 + nf * 16 + l15;
        int kb = kc * 64 + l4 * 16;
        bb[nf][kc] = *(const bf16x8*)(lds + 16384 + row * 128 + (kb ^ ((row & 7) << 4)));
      }
#pragma unroll
    for (int kc = 0; kc < 2; ++kc)
#pragma unroll
      for (int mf = 0; mf < 4; ++mf)
#pragma unroll
        for (int nf = 0; nf < 4; ++nf)
          acc[mf][nf] = mfma16(a[mf][kc], bb[nf][kc], acc[mf][nf]);
    __syncthreads();
  }

  const float* bias = (sel == 0) ? bq : (sel == 1) ? bk : bv;
  float postScale = (sel == 0) ? 0.5f : 1.0f;
#pragma unroll
  for (int nf = 0; nf < 4; ++nf) {
    int n = n0 + wc * 64 + nf * 16 + l15;
    int h = n >> 6, e = n & 63;
    float bv_ = bias[n];
#pragma unroll
    for (int mf = 0; mf < 4; ++mf) {
      int mrow0 = m0 + wr * 64 + mf * 16 + l4 * 4;
      int b_ = mrow0 >> 10, s0 = mrow0 & 1023;
      if (sel == 2) {
        ushort4 pk;
        pk.x = f2b(acc[mf][nf][0] + bv_);
        pk.y = f2b(acc[mf][nf][1] + bv_);
        pk.z = f2b(acc[mf][nf][2] + bv_);
        pk.w = f2b(acc[mf][nf][3] + bv_);
        *(ushort4*)(Vtb + ((size_t)(b_ * NHEAD + h) * NHID + e) * S_LEN + s0) = pk;
      } else {
        u16* dst = (sel == 0) ? Qb : Kb;
#pragma unroll
        for (int j = 0; j < 4; ++j)
          dst[((size_t)(b_ * NHEAD + h) * S_LEN + s0 + j) * NHID + e] =
              f2b((acc[mf][nf][j] + bv_) * postScale);
      }
    }
  }
}

// ---------------- fused attention ----------------
// grid (64 qtiles, 64 bh), 4 waves; block = 16 q rows; wave owns a 256-key slice.
// VGPR target <=128 -> 4 blocks/CU. LDS ~19KB.
__global__ __launch_bounds__(256, 4) void k_attn(const u16* __restrict__ Qb,
                                                 const u16* __restrict__ Kb,
                                                 const u16* __restrict__ Vtb,
                                                 const uint32_t* __restrict__ mbitsG,
                                                 float* __restrict__ alphaOut,
                                                 u16* __restrict__ Ob) {
  __shared__ __align__(16) char smem[19072];
  uint32_t* mbits = (uint32_t*)smem;        // [16 q][33 words] padded = 2112B (+pad)
  float* redM = (float*)(smem + 2176);      // [64]
  float* redS = (float*)(smem + 2432);      // [64]
  char* chunkB = smem + 2688;               // [4 w][2 buf][2048]
  int t = threadIdx.x, w = t >> 6, lane = t & 63;
  int l15 = lane & 15, l4 = lane >> 4;
  int q0 = blockIdx.x * 16;
  int bh = blockIdx.y, b = bh >> 4, hh = bh & 15;
  const u16* Qh = Qb + (size_t)bh * S_LEN * NHID;
  const u16* Kh = Kb + (size_t)bh * S_LEN * NHID;
  const u16* Vh = Vtb + (size_t)bh * NHID * S_LEN;
  int kbase = w * 256;

  // mask bits: 16 rows x 32 words = 512 u32; each thread loads uint2
  uint2 mw2 = ((const uint2*)(mbitsG + ((size_t)b * S_LEN + q0) * 32))[t];

  // Q fragments (pre-scaled by 0.5): row = l15, k = ec*32 + l4*8
  bf16x8 aq[2];
#pragma unroll
  for (int ec = 0; ec < 2; ++ec)
    aq[ec] = *(const bf16x8*)(Qh + (size_t)(q0 + l15) * NHID + ec * 32 + l4 * 8);

  {
    int row = t >> 4, c0 = (t & 15) * 2;
    mbits[row * 33 + c0 + 0] = mw2.x;
    mbits[row * 33 + c0 + 1] = mw2.y;
  }

  // QK^T: sc[kf] = D[q=l4*4+j][key=kbase+kf*16+l15]
  f32x4 sc[16];
  const f32x4 fz = {0.f, 0.f, 0.f, 0.f};
#pragma unroll
  for (int kf = 0; kf < 16; ++kf) sc[kf] = fz;

#pragma unroll
  for (int kf = 0; kf < 16; ++kf) {
    int key = kbase + kf * 16 + l15;
    bf16x8 kb0 = *(const bf16x8*)(Kh + (size_t)key * NHID + l4 * 8);
    bf16x8 kb1 = *(const bf16x8*)(Kh + (size_t)key * NHID + 32 + l4 * 8);
    sc[kf] = mfma16(aq[0], kb0, sc[kf]);
    sc[kf] = mfma16(aq[1], kb1, sc[kf]);
  }

  // row max: over kf, then 16-lane shuffle group, then cross-wave via LDS
  float rm[4];
#pragma unroll
  for (int j = 0; j < 4; ++j) {
    float m = sc[0][j];
#pragma unroll
    for (int kf = 1; kf < 16; ++kf) m = fmaxf(m, sc[kf][j]);
    rm[j] = m;
  }
#pragma unroll
  for (int msk = 1; msk < 16; msk <<= 1)
#pragma unroll
    for (int j = 0; j < 4; ++j) rm[j] = fmaxf(rm[j], __shfl_xor(rm[j], msk));
  if (l15 == 0) {
#pragma unroll
    for (int j = 0; j < 4; ++j) redM[w * 16 + l4 * 4 + j] = rm[j];
  }
  __syncthreads();
  float Mx[4];
#pragma unroll
  for (int j = 0; j < 4; ++j) {
    int row = l4 * 4 + j;
    Mx[j] = fmaxf(fmaxf(redM[row], redM[16 + row]),
                  fmaxf(redM[32 + row], redM[48 + row]));
  }

  // exp + row sum
  float ls[4] = {0.f, 0.f, 0.f, 0.f};
#pragma unroll
  for (int kf = 0; kf < 16; ++kf)
#pragma unroll
    for (int j = 0; j < 4; ++j) {
      float p = __expf(sc[kf][j] - Mx[j]);
      sc[kf][j] = p;
      ls[j] += p;
    }
#pragma unroll
  for (int msk = 1; msk < 16; msk <<= 1)
#pragma unroll
    for (int j = 0; j < 4; ++j) ls[j] += __shfl_xor(ls[j], msk);
  if (l15 == 0) {
#pragma unroll
    for (int j = 0; j < 4; ++j) redS[w * 16 + l4 * 4 + j] = ls[j];
  }
  __syncthreads();
  float inv[4];
#pragma unroll
  for (int j = 0; j < 4; ++j) {
    int row = l4 * 4 + j;
    inv[j] = 1.f / (redS[row] + redS[16 + row] + redS[32 + row] + redS[48 + row]);
  }

  float* abW = alphaOut + (size_t)bh * S_LEN * S_LEN;

  f32x4 o[4];
#pragma unroll
  for (int ef = 0; ef < 4; ++ef) o[ef] = fz;

  // chunk = 64 keys. produce: mask+normalize+global write+LDS bf16 stage.
  auto produce = [&](int c) {
    char* buf = chunkB + (w * 2 + (c & 1)) * 2048;
    int widxBase = w * 8 + c * 2;
#pragma unroll
    for (int f = 0; f < 4; ++f) {
      int kf = c * 4 + f;
      int keyg = kbase + kf * 16 + l15;
      int widx = widxBase + (f >> 1);
      int bitpos = ((f & 1) << 4) + l15;
#pragma unroll
      for (int j = 0; j < 4; ++j) {
        int row = l4 * 4 + j;
        uint32_t mwd = mbits[row * 33 + widx];
        float av = ((mwd >> bitpos) & 1u) ? sc[kf][j] * inv[j] : 0.f;
        __builtin_nontemporal_store(av, abW + (size_t)(q0 + row) * S_LEN + keyg);
        int klc = f * 16 + l15;
        *(u16*)(buf + row * 128 + ((2 * klc) ^ ((row & 7) << 4))) = f2b(av);
      }
    }
  };
  auto pv = [&](int c) {
    char* buf = chunkB + (w * 2 + (c & 1)) * 2048;
#pragma unroll
    for (int kc2 = 0; kc2 < 2; ++kc2) {
      int qrow = l15;
      bf16x8 pa = *(const bf16x8*)(buf + qrow * 128 +
                                   ((kc2 * 64 + l4 * 16) ^ ((qrow & 7) << 4)));
#pragma unroll
      for (int ef = 0; ef < 4; ++ef) {
        int e = ef * 16 + l15;
        bf16x8 vb = *(const bf16x8*)(Vh + (size_t)e * S_LEN + kbase + c * 64 +
                                     kc2 * 32 + l4 * 8);
        o[ef] = mfma16(pa, vb, o[ef]);
      }
    }
  };

  produce(0);
  produce(1); pv(0);
  produce(2); pv(1);
  produce(3); pv(2);
  pv(3);

  // cross-wave O reduction (16KB, aliases chunk region)
  __syncthreads();
  float* redO = (float*)chunkB; // [4 w][16 q][64 e]
#pragma unroll
  for (int ef = 0; ef < 4; ++ef)
#pragma unroll
    for (int j = 0; j < 4; ++j)
      redO[w * 1024 + (l4 * 4 + j) * 64 + ef * 16 + l15] = o[ef][j];
  __syncthreads();
  {
    int e = t & 63, r4 = t >> 6;
#pragma unroll
    for (int p = 0; p < 4; ++p) {
      int r = p * 4 + r4;
      float s4 = redO[r * 64 + e] + redO[1024 + r * 64 + e] +
                 redO[2048 + r * 64 + e] + redO[3072 + r * 64 + e];
      Ob[(size_t)(b * S_LEN + q0 + r) * DIM + hh * NHID + e] = f2b(s4);
    }
  }
}

// ---------------- output projection ----------------
__global__ __launch_bounds__(256) void k_oproj(const u16* __restrict__ Ob,
                                               const u16* __restrict__ Wotb,
                                               const float* __restrict__ bo,
                                               float* __restrict__ out) {
  __shared__ __align__(16) char lds[32768];
  int t = threadIdx.x, w = t >> 6, lane = t & 63;
  int l15 = lane & 15, l4 = lane >> 4;
  int m0 = blockIdx.x * 128, n0 = blockIdx.y * 128;
  int wr = w >> 1, wc = w & 1;
  f32x4 acc[4][4];
  const f32x4 fz = {0.f, 0.f, 0.f, 0.f};
#pragma unroll
  for (int i = 0; i < 4; ++i)
#pragma unroll
    for (int j = 0; j < 4; ++j) acc[i][j] = fz;

  for (int kk = 0; kk < 16; ++kk) {
    int k0 = kk * 64;
#pragma unroll
    for (int c = 0; c < 4; ++c) {
      int idx = c * 256 + t, r = idx >> 3, cb = idx & 7;
      int4 v = *(const int4*)(Ob + (size_t)(m0 + r) * DIM + k0 + cb * 8);
      *(int4*)(lds + r * 128 + ((cb * 16) ^ ((r & 7) << 4))) = v;
    }
#pragma unroll
    for (int c = 0; c < 4; ++c) {
      int idx = c * 256 + t, r = idx >> 3, cb = idx & 7;
      int4 v = *(const int4*)(Wotb + (size_t)(n0 + r) * DIM + k0 + cb * 8);
      *(int4*)(lds + 16384 + r * 128 + ((cb * 16) ^ ((r & 7) << 4))) = v;
    }
    __syncthreads();
    bf16x8 a[4][2], bb[4][2];
#pragma unroll
    for (int mf = 0; mf < 4; ++mf)
#pragma unroll
      for (int kc = 0; kc < 2; ++kc) {
        int row = wr * 64 + mf * 16 + l15;
        int kb = kc * 64 + l4 * 16;
        a[mf][kc] = *(const bf16x8*)(lds + row * 128 + (kb ^ ((row & 7) << 4)));
      }
#pragma unroll
    for (int nf = 0; nf < 4; ++nf)
#pragma unroll
      for (int kc = 0; kc < 2; ++kc) {
        int row = wc * 64 + nf * 16 + l15;
        int kb = kc * 64 + l4 * 16;
        bb[nf][kc] = *(const bf16x8*)(lds + 16384 + row * 128 + (kb ^ ((row & 7) << 4)));
      }
#pragma unroll
    for (int kc = 0; kc < 2; ++kc)
#pragma unroll
      for (int mf = 0; mf < 4; ++mf)
#pragma unroll
        for (int nf = 0; nf < 4; ++nf)
          acc[mf][nf] = mfma16(a[mf][kc], bb[nf][kc], acc[mf][nf]);
    __syncthreads();
  }
#pragma unroll
  for (int nf = 0; nf < 4; ++nf) {
    int n = n0 + wc * 64 + nf * 16 + l15;
    float bv_ = bo[n];
#pragma unroll
    for (int mf = 0; mf < 4; ++mf)
#pragma unroll
      for (int j = 0; j < 4; ++j) {
        int m = m0 + wr * 64 + mf * 16 + l4 * 4 + j;
        out[(size_t)m * DIM + n] = acc[mf][nf][j] + bv_;
      }
  }
}

extern "C" void kernel_launch(void* const* d_in, const int* in_sizes, int n_in,
                              void* d_out, int out_size, void* d_ws, size_t ws_size,
                              hipStream_t stream) {
  const float* x    = (const float*)d_in[0];
  const int*   mask = (const int*)d_in[1];
  const float* Wq   = (const float*)d_in[2];
  const float* bq   = (const float*)d_in[3];
  const float* Wk   = (const float*)d_in[4];
  const float* bk   = (const float*)d_in[5];
  const float* Wv   = (const float*)d_in[6];
  const float* bv   = (const float*)d_in[7];
  const float* Wo   = (const float*)d_in[8];
  const float* bo   = (const float*)d_in[9];
  float* out = (float*)d_out;
  float* alphaOut = out + (size_t)NB * S_LEN * DIM;

  char* ws = (char*)d_ws;
  u16* xb    = (u16*)(ws);             // 8,388,608 B
  u16* Wtb   = (u16*)(ws + 8388608);   // 6,291,456 B
  u16* Wotb  = (u16*)(ws + 14680064);  // 2,097,152 B
  u16* Qb    = (u16*)(ws + 16777216);  // 8,388,608 B
  u16* Kb    = (u16*)(ws + 25165824);  // 8,388,608 B
  u16* Vtb   = (u16*)(ws + 33554432);  // 8,388,608 B
  u16* Ob    = (u16*)(ws + 41943040);  // 8,388,608 B
  uint32_t* mbits = (uint32_t*)(ws + 50331648); // 524,288 B

  k_maskbits<<<512, 256, 0, stream>>>(mask, mbits);
  k_cvt_x<<<4096, 256, 0, stream>>>(x, xb);
  k_transpose<<<dim3(16, 32, 1), 256, 0, stream>>>(Wq, Wtb,           1024, 64);
  k_transpose<<<dim3(16, 32, 1), 256, 0, stream>>>(Wk, Wtb + 1048576, 1024, 64);
  k_transpose<<<dim3(16, 32, 1), 256, 0, stream>>>(Wv, Wtb + 2097152, 1024, 64);
  k_transpose<<<dim3(1, 32, 16), 256, 0, stream>>>(Wo, Wotb,          1024, 1024);
  k_qkv<<<dim3(32, 8, 3), 256, 0, stream>>>(xb, Wtb, bq, bk, bv, Qb, Kb, Vtb);
  k_attn<<<dim3(64, 64), 256, 0, stream>>>(Qb, Kb, Vtb, mbits, alphaOut, Ob);
  k_oproj<<<dim3(32, 8), 256, 0, stream>>>(Ob, Wotb, bo, out);
}